// Round 1
// baseline (320.605 us; speedup 1.0000x reference)
//
#include <hip/hip_runtime.h>
#include <cstdint>

typedef unsigned short u16;
typedef __attribute__((ext_vector_type(8))) short short8;
typedef __attribute__((ext_vector_type(4))) float f32x4;
typedef __attribute__((ext_vector_type(4))) unsigned short u16x4;

__device__ __forceinline__ u16 f2bf(float x) {
    unsigned int u = __float_as_uint(x);
    u += 0x7fffu + ((u >> 16) & 1u);
    return (u16)(u >> 16);
}

__device__ __forceinline__ void gload_lds16(const u16* g, u16* l) {
    __builtin_amdgcn_global_load_lds(
        (const __attribute__((address_space(1))) void*)(g),
        (__attribute__((address_space(3))) void*)(l),
        16, 0, 0);
}

// ---------------- cast x (fp32 -> bf16), 4 elems/thread ----------------
__global__ __launch_bounds__(256) void cast_x_kernel(const float* __restrict__ x,
                                                     u16* __restrict__ xb) {
    int i = (blockIdx.x * 256 + threadIdx.x) * 4;
    float4 v = *(const float4*)(x + i);
    u16x4 o;
    o.x = f2bf(v.x); o.y = f2bf(v.y); o.z = f2bf(v.z); o.w = f2bf(v.w);
    *(u16x4*)(xb + i) = o;
}

// ---------------- transpose+cast: dst[c][r] = src[r][c], per-matrix z ----------------
__global__ __launch_bounds__(256) void transpose_cast_kernel(const float* __restrict__ src,
                                                             u16* __restrict__ dst,
                                                             int R, int C) {
    __shared__ u16 tile[64][65];
    const int rb = blockIdx.x * 64, cb = blockIdx.y * 64;
    const size_t matoff = (size_t)blockIdx.z * R * C;
    src += matoff; dst += matoff;
    const int tc = threadIdx.x & 63, tr = threadIdx.x >> 6;
    #pragma unroll
    for (int i = 0; i < 64; i += 4)
        tile[tr + i][tc] = f2bf(src[(size_t)(rb + tr + i) * C + (cb + tc)]);
    __syncthreads();
    #pragma unroll
    for (int i = 0; i < 64; i += 4)
        dst[(size_t)(cb + tr + i) * R + (rb + tc)] = tile[tc][tr + i];
}

// ---------------- QKV GEMM: [4096,1024] x [3072,1024]^T, m97-style ----------------
// Epilogue: +bias; Q *= 0.125 -> q[bh][s][64]; K -> k[bh][t][64]; V -> vt[bh][64][t] (transposed)
__global__ __launch_bounds__(256) void gemm_qkv_kernel(
    const u16* __restrict__ X, const u16* __restrict__ W,
    const float* __restrict__ bq, const float* __restrict__ bk,
    const float* __restrict__ bv,
    u16* __restrict__ qo, u16* __restrict__ ko, u16* __restrict__ vto)
{
    __shared__ __align__(16) u16 As[128 * 32];
    __shared__ __align__(16) u16 Bs[128 * 32];
    const int tid = threadIdx.x;
    const int lane = tid & 63;
    const int wv = tid >> 6;
    const int wm = wv & 1, wn = wv >> 1;
    const int m0 = blockIdx.x * 128;
    const int n0 = blockIdx.y * 128;
    const int c = lane & 15, qd = lane >> 4;

    f32x4 acc[4][4];
    #pragma unroll
    for (int a = 0; a < 4; ++a)
        #pragma unroll
        for (int b2 = 0; b2 < 4; ++b2) acc[a][b2] = f32x4{0.f, 0.f, 0.f, 0.f};

    const u16* Xb = X + (size_t)m0 * 1024;
    const u16* Wb = W + (size_t)n0 * 1024;

    for (int kt = 0; kt < 1024; kt += 32) {
        #pragma unroll
        for (int i = 0; i < 2; ++i) {
            int slot = i * 256 + tid;
            int row = slot >> 2, part = slot & 3;
            gload_lds16(Xb + (size_t)row * 1024 + kt + part * 8, &As[slot * 8]);
            gload_lds16(Wb + (size_t)row * 1024 + kt + part * 8, &Bs[slot * 8]);
        }
        __syncthreads();
        short8 af[4], bf[4];
        #pragma unroll
        for (int mt = 0; mt < 4; ++mt)
            af[mt] = *(const short8*)&As[(wm * 64 + mt * 16 + c) * 32 + qd * 8];
        #pragma unroll
        for (int nt = 0; nt < 4; ++nt)
            bf[nt] = *(const short8*)&Bs[(wn * 64 + nt * 16 + c) * 32 + qd * 8];
        #pragma unroll
        for (int mt = 0; mt < 4; ++mt)
            #pragma unroll
            for (int nt = 0; nt < 4; ++nt)
                acc[mt][nt] = __builtin_amdgcn_mfma_f32_16x16x32_bf16(af[mt], bf[nt], acc[mt][nt], 0, 0, 0);
        __syncthreads();
    }

    // epilogue: n -> (mat, h, e); m -> (b, s)
    #pragma unroll
    for (int mt = 0; mt < 4; ++mt) {
        const int mbase = m0 + wm * 64 + mt * 16 + qd * 4;
        const int b = mbase >> 11;
        #pragma unroll
        for (int nt = 0; nt < 4; ++nt) {
            const int n = n0 + wn * 64 + nt * 16 + c;
            const int mat = n >> 10;
            const int idx = n & 1023;
            const int h = idx >> 6, e = idx & 63;
            const float bias = (mat == 0 ? bq : (mat == 1 ? bk : bv))[idx];
            if (mat == 2) {
                const int s = mbase & 2047;
                u16x4 pv;
                pv.x = f2bf(acc[mt][nt][0] + bias);
                pv.y = f2bf(acc[mt][nt][1] + bias);
                pv.z = f2bf(acc[mt][nt][2] + bias);
                pv.w = f2bf(acc[mt][nt][3] + bias);
                *(u16x4*)(vto + ((size_t)((b * 16 + h) * 64 + e)) * 2048 + s) = pv;
            } else {
                const float scale = (mat == 0) ? 0.125f : 1.0f;
                u16* dst = (mat == 0) ? qo : ko;
                #pragma unroll
                for (int r = 0; r < 4; ++r) {
                    const int s = (mbase + r) & 2047;
                    dst[((size_t)((b * 16 + h) * 2048 + s)) * 64 + e] =
                        f2bf((acc[mt][nt][r] + bias) * scale);
                }
            }
        }
    }
}

// ---------------- flash attention: 128 Q rows/block, 64-key tiles ----------------
__global__ __launch_bounds__(256) void flash_kernel(
    const u16* __restrict__ Q,   // [32][2048][64], pre-scaled by 1/8
    const u16* __restrict__ K,   // [32][2048][64]
    const u16* __restrict__ Vt,  // [32][64][2048]
    u16* __restrict__ ctx)       // [4096][1024] = [b*2048+s][h*64+e]
{
    __shared__ __align__(16) u16 Ks[64 * 72];
    __shared__ __align__(16) u16 Vs[64 * 72];
    __shared__ __align__(16) u16 Ps[128 * 72];
    const int tid = threadIdx.x, lane = tid & 63, w = tid >> 6;
    const int c = lane & 15, qd = lane >> 4;
    const int bh = blockIdx.y;
    const int q0 = blockIdx.x * 128;
    const int b = bh >> 4, h = bh & 15;
    const u16* Qh = Q + (size_t)bh * 2048 * 64;
    const u16* Kh = K + (size_t)bh * 2048 * 64;
    const u16* Vh = Vt + (size_t)bh * 64 * 2048;

    // Q A-fragments stay in registers for all 32 key-tiles
    short8 qa[2][2];
    #pragma unroll
    for (int mt = 0; mt < 2; ++mt)
        #pragma unroll
        for (int kb = 0; kb < 2; ++kb)
            qa[mt][kb] = *(const short8*)&Qh[(size_t)(q0 + w * 32 + mt * 16 + c) * 64 + kb * 32 + qd * 8];

    f32x4 o[2][4];
    float mrow[2][4], lrow[2][4];
    #pragma unroll
    for (int mt = 0; mt < 2; ++mt) {
        #pragma unroll
        for (int nt = 0; nt < 4; ++nt) o[mt][nt] = f32x4{0.f, 0.f, 0.f, 0.f};
        #pragma unroll
        for (int r = 0; r < 4; ++r) { mrow[mt][r] = -__builtin_inff(); lrow[mt][r] = 0.f; }
    }

    for (int t0 = 0; t0 < 2048; t0 += 64) {
        // stage K tile [64][64] -> Ks[64][72], Vt tile [64 e][64 t] -> Vs[64][72]
        #pragma unroll
        for (int i = 0; i < 2; ++i) {
            int sl = i * 256 + tid;
            int r = sl >> 3, p = sl & 7;
            *(short8*)&Ks[r * 72 + p * 8] = *(const short8*)&Kh[(size_t)(t0 + r) * 64 + p * 8];
            *(short8*)&Vs[r * 72 + p * 8] = *(const short8*)&Vh[(size_t)r * 2048 + t0 + p * 8];
        }
        __syncthreads();

        // S = Q K^T  (scale folded into Q)
        f32x4 sc[2][4];
        #pragma unroll
        for (int mt = 0; mt < 2; ++mt)
            #pragma unroll
            for (int nt = 0; nt < 4; ++nt) sc[mt][nt] = f32x4{0.f, 0.f, 0.f, 0.f};
        #pragma unroll
        for (int nt = 0; nt < 4; ++nt)
            #pragma unroll
            for (int kb = 0; kb < 2; ++kb) {
                short8 kf = *(const short8*)&Ks[(nt * 16 + c) * 72 + kb * 32 + qd * 8];
                sc[0][nt] = __builtin_amdgcn_mfma_f32_16x16x32_bf16(qa[0][kb], kf, sc[0][nt], 0, 0, 0);
                sc[1][nt] = __builtin_amdgcn_mfma_f32_16x16x32_bf16(qa[1][kb], kf, sc[1][nt], 0, 0, 0);
            }

        // online softmax over this tile's 64 keys
        float mnew[2][4];
        #pragma unroll
        for (int mt = 0; mt < 2; ++mt)
            #pragma unroll
            for (int r = 0; r < 4; ++r)
                mnew[mt][r] = fmaxf(fmaxf(sc[mt][0][r], sc[mt][1][r]),
                                    fmaxf(sc[mt][2][r], sc[mt][3][r]));
        #pragma unroll
        for (int off = 1; off < 16; off <<= 1)
            #pragma unroll
            for (int mt = 0; mt < 2; ++mt)
                #pragma unroll
                for (int r = 0; r < 4; ++r)
                    mnew[mt][r] = fmaxf(mnew[mt][r], __shfl_xor(mnew[mt][r], off, 64));

        float al[2][4], rs[2][4];
        #pragma unroll
        for (int mt = 0; mt < 2; ++mt)
            #pragma unroll
            for (int r = 0; r < 4; ++r) {
                float mn = fmaxf(mrow[mt][r], mnew[mt][r]);
                al[mt][r] = __expf(mrow[mt][r] - mn);
                mrow[mt][r] = mn;
                rs[mt][r] = 0.f;
            }
        #pragma unroll
        for (int mt = 0; mt < 2; ++mt)
            #pragma unroll
            for (int nt = 0; nt < 4; ++nt)
                #pragma unroll
                for (int r = 0; r < 4; ++r) {
                    float p = __expf(sc[mt][nt][r] - mrow[mt][r]);
                    sc[mt][nt][r] = p;
                    rs[mt][r] += p;
                }
        #pragma unroll
        for (int off = 1; off < 16; off <<= 1)
            #pragma unroll
            for (int mt = 0; mt < 2; ++mt)
                #pragma unroll
                for (int r = 0; r < 4; ++r)
                    rs[mt][r] += __shfl_xor(rs[mt][r], off, 64);
        #pragma unroll
        for (int mt = 0; mt < 2; ++mt)
            #pragma unroll
            for (int r = 0; r < 4; ++r)
                lrow[mt][r] = lrow[mt][r] * al[mt][r] + rs[mt][r];
        #pragma unroll
        for (int mt = 0; mt < 2; ++mt)
            #pragma unroll
            for (int nt = 0; nt < 4; ++nt)
                #pragma unroll
                for (int r = 0; r < 4; ++r)
                    o[mt][nt][r] *= al[mt][r];

        // P: C-layout -> LDS (bf16) -> A-layout
        #pragma unroll
        for (int mt = 0; mt < 2; ++mt)
            #pragma unroll
            for (int nt = 0; nt < 4; ++nt)
                #pragma unroll
                for (int r = 0; r < 4; ++r)
                    Ps[(w * 32 + mt * 16 + qd * 4 + r) * 72 + nt * 16 + c] = f2bf(sc[mt][nt][r]);

        // O += P V
        #pragma unroll
        for (int kb = 0; kb < 2; ++kb) {
            short8 pa0 = *(const short8*)&Ps[(w * 32 + c) * 72 + kb * 32 + qd * 8];
            short8 pa1 = *(const short8*)&Ps[(w * 32 + 16 + c) * 72 + kb * 32 + qd * 8];
            #pragma unroll
            for (int nt = 0; nt < 4; ++nt) {
                short8 vf = *(const short8*)&Vs[(nt * 16 + c) * 72 + kb * 32 + qd * 8];
                o[0][nt] = __builtin_amdgcn_mfma_f32_16x16x32_bf16(pa0, vf, o[0][nt], 0, 0, 0);
                o[1][nt] = __builtin_amdgcn_mfma_f32_16x16x32_bf16(pa1, vf, o[1][nt], 0, 0, 0);
            }
        }
        __syncthreads();
    }

    // normalize + store ctx (bf16) in [b*2048+s][h*64+e]
    float inv[2][4];
    #pragma unroll
    for (int mt = 0; mt < 2; ++mt)
        #pragma unroll
        for (int r = 0; r < 4; ++r) inv[mt][r] = 1.0f / lrow[mt][r];
    #pragma unroll
    for (int mt = 0; mt < 2; ++mt)
        #pragma unroll
        for (int nt = 0; nt < 4; ++nt)
            #pragma unroll
            for (int r = 0; r < 4; ++r) {
                int srow = q0 + w * 32 + mt * 16 + qd * 4 + r;
                ctx[((size_t)(b * 2048 + srow)) * 1024 + h * 64 + nt * 16 + c] =
                    f2bf(o[mt][nt][r] * inv[mt][r]);
            }
}

// ---------------- output projection: ctx[4096,1024] x Wo^T[1024,1024] + bo ----------------
__global__ __launch_bounds__(256) void gemm_out_kernel(
    const u16* __restrict__ A, const u16* __restrict__ Wt,
    const float* __restrict__ bo, float* __restrict__ out)
{
    __shared__ __align__(16) u16 As[128 * 32];
    __shared__ __align__(16) u16 Bs[128 * 32];
    const int tid = threadIdx.x;
    const int lane = tid & 63;
    const int wv = tid >> 6;
    const int wm = wv & 1, wn = wv >> 1;
    const int m0 = blockIdx.x * 128;
    const int n0 = blockIdx.y * 128;
    const int c = lane & 15, qd = lane >> 4;

    f32x4 acc[4][4];
    #pragma unroll
    for (int a = 0; a < 4; ++a)
        #pragma unroll
        for (int b2 = 0; b2 < 4; ++b2) acc[a][b2] = f32x4{0.f, 0.f, 0.f, 0.f};

    const u16* Ab = A + (size_t)m0 * 1024;
    const u16* Wb = Wt + (size_t)n0 * 1024;

    for (int kt = 0; kt < 1024; kt += 32) {
        #pragma unroll
        for (int i = 0; i < 2; ++i) {
            int slot = i * 256 + tid;
            int row = slot >> 2, part = slot & 3;
            gload_lds16(Ab + (size_t)row * 1024 + kt + part * 8, &As[slot * 8]);
            gload_lds16(Wb + (size_t)row * 1024 + kt + part * 8, &Bs[slot * 8]);
        }
        __syncthreads();
        short8 af[4], bf[4];
        #pragma unroll
        for (int mt = 0; mt < 4; ++mt)
            af[mt] = *(const short8*)&As[(wm * 64 + mt * 16 + c) * 32 + qd * 8];
        #pragma unroll
        for (int nt = 0; nt < 4; ++nt)
            bf[nt] = *(const short8*)&Bs[(wn * 64 + nt * 16 + c) * 32 + qd * 8];
        #pragma unroll
        for (int mt = 0; mt < 4; ++mt)
            #pragma unroll
            for (int nt = 0; nt < 4; ++nt)
                acc[mt][nt] = __builtin_amdgcn_mfma_f32_16x16x32_bf16(af[mt], bf[nt], acc[mt][nt], 0, 0, 0);
        __syncthreads();
    }

    #pragma unroll
    for (int mt = 0; mt < 4; ++mt) {
        const int mbase = m0 + wm * 64 + mt * 16 + qd * 4;
        #pragma unroll
        for (int nt = 0; nt < 4; ++nt) {
            const int n = n0 + wn * 64 + nt * 16 + c;
            const float bias = bo[n];
            #pragma unroll
            for (int r = 0; r < 4; ++r)
                out[(size_t)(mbase + r) * 1024 + n] = acc[mt][nt][r] + bias;
        }
    }
}

extern "C" void kernel_launch(void* const* d_in, const int* in_sizes, int n_in,
                              void* d_out, int out_size, void* d_ws, size_t ws_size,
                              hipStream_t stream) {
    const float* x  = (const float*)d_in[0];
    const float* Wq = (const float*)d_in[1];
    const float* bq = (const float*)d_in[2];
    const float* Wk = (const float*)d_in[3];
    const float* bk = (const float*)d_in[4];
    const float* Wv = (const float*)d_in[5];
    const float* bv = (const float*)d_in[6];
    const float* Wo = (const float*)d_in[7];
    const float* bo = (const float*)d_in[8];
    float* out = (float*)d_out;

    u16* ws    = (u16*)d_ws;
    u16* xb    = ws;                          // 4096*1024
    u16* wqkv  = xb + 4096 * 1024;            // 3072*1024  (rows n=(mat,h,e), cols k=d)
    u16* wot   = wqkv + 3072 * 1024;          // 1024*1024  (rows n=o, cols k=d)
    u16* qws   = wot + 1024 * 1024;           // 32*2048*64
    u16* kws   = qws + 4194304;               // 32*2048*64
    u16* vtws  = kws + 4194304;               // 32*64*2048
    u16* ctxws = vtws + 4194304;              // 4096*1024

    cast_x_kernel<<<4096, 256, 0, stream>>>(x, xb);
    transpose_cast_kernel<<<dim3(16, 1, 16), 256, 0, stream>>>(Wq, wqkv, 1024, 64);
    transpose_cast_kernel<<<dim3(16, 1, 16), 256, 0, stream>>>(Wk, wqkv + 1024 * 1024, 1024, 64);
    transpose_cast_kernel<<<dim3(16, 1, 16), 256, 0, stream>>>(Wv, wqkv + 2 * 1024 * 1024, 1024, 64);
    transpose_cast_kernel<<<dim3(16, 16, 1), 256, 0, stream>>>(Wo, wot, 1024, 1024);
    gemm_qkv_kernel<<<dim3(32, 24), 256, 0, stream>>>(xb, wqkv, bq, bk, bv, qws, kws, vtws);
    flash_kernel<<<dim3(16, 32), 256, 0, stream>>>(qws, kws, vtws, ctxws);
    gemm_out_kernel<<<dim3(32, 8), 256, 0, stream>>>(ctxws, wot, bo, out);
}

// Round 2
// 251.449 us; speedup vs baseline: 1.2750x; 1.2750x over previous
//
#include <hip/hip_runtime.h>
#include <cstdint>

typedef unsigned short u16;
typedef __attribute__((ext_vector_type(8))) short short8;
typedef __attribute__((ext_vector_type(4))) float f32x4;
typedef __attribute__((ext_vector_type(4))) unsigned short u16x4;

__device__ __forceinline__ u16 f2bf(float x) {
    unsigned int u = __float_as_uint(x);
    u += 0x7fffu + ((u >> 16) & 1u);
    return (u16)(u >> 16);
}

__device__ __forceinline__ void gload_lds16(const u16* g, u16* l) {
    __builtin_amdgcn_global_load_lds(
        (const __attribute__((address_space(1))) void*)(g),
        (__attribute__((address_space(3))) void*)(l),
        16, 0, 0);
}

// ---------------- cast x (fp32 -> bf16), 4 elems/thread ----------------
__global__ __launch_bounds__(256) void cast_x_kernel(const float* __restrict__ x,
                                                     u16* __restrict__ xb) {
    int i = (blockIdx.x * 256 + threadIdx.x) * 4;
    float4 v = *(const float4*)(x + i);
    u16x4 o;
    o.x = f2bf(v.x); o.y = f2bf(v.y); o.z = f2bf(v.z); o.w = f2bf(v.w);
    *(u16x4*)(xb + i) = o;
}

// ---------------- transpose+cast: dst[c][r] = src[r][c], per-matrix z ----------------
__global__ __launch_bounds__(256) void transpose_cast_kernel(const float* __restrict__ src,
                                                             u16* __restrict__ dst,
                                                             int R, int C) {
    __shared__ u16 tile[64][65];
    const int rb = blockIdx.x * 64, cb = blockIdx.y * 64;
    const size_t matoff = (size_t)blockIdx.z * R * C;
    src += matoff; dst += matoff;
    const int tc = threadIdx.x & 63, tr = threadIdx.x >> 6;
    #pragma unroll
    for (int i = 0; i < 64; i += 4)
        tile[tr + i][tc] = f2bf(src[(size_t)(rb + tr + i) * C + (cb + tc)]);
    __syncthreads();
    #pragma unroll
    for (int i = 0; i < 64; i += 4)
        dst[(size_t)(cb + tr + i) * R + (rb + tc)] = tile[tc][tr + i];
}

// ---------------- QKV GEMM: [4096,1024] x [3072,1024]^T, m97-style ----------------
// Epilogue: +bias; Q *= 0.125 -> q[bh][s][64]; K -> k[bh][t][64]; V -> vt[bh][64][t] (transposed)
__global__ __launch_bounds__(256) void gemm_qkv_kernel(
    const u16* __restrict__ X, const u16* __restrict__ W,
    const float* __restrict__ bq, const float* __restrict__ bk,
    const float* __restrict__ bv,
    u16* __restrict__ qo, u16* __restrict__ ko, u16* __restrict__ vto)
{
    __shared__ __align__(16) u16 As[128 * 32];
    __shared__ __align__(16) u16 Bs[128 * 32];
    const int tid = threadIdx.x;
    const int lane = tid & 63;
    const int wv = tid >> 6;
    const int wm = wv & 1, wn = wv >> 1;
    const int m0 = blockIdx.x * 128;
    const int n0 = blockIdx.y * 128;
    const int c = lane & 15, qd = lane >> 4;

    f32x4 acc[4][4];
    #pragma unroll
    for (int a = 0; a < 4; ++a)
        #pragma unroll
        for (int b2 = 0; b2 < 4; ++b2) acc[a][b2] = f32x4{0.f, 0.f, 0.f, 0.f};

    const u16* Xb = X + (size_t)m0 * 1024;
    const u16* Wb = W + (size_t)n0 * 1024;

    for (int kt = 0; kt < 1024; kt += 32) {
        #pragma unroll
        for (int i = 0; i < 2; ++i) {
            int slot = i * 256 + tid;
            int row = slot >> 2, part = slot & 3;
            gload_lds16(Xb + (size_t)row * 1024 + kt + part * 8, &As[slot * 8]);
            gload_lds16(Wb + (size_t)row * 1024 + kt + part * 8, &Bs[slot * 8]);
        }
        __syncthreads();
        short8 af[4], bf[4];
        #pragma unroll
        for (int mt = 0; mt < 4; ++mt)
            af[mt] = *(const short8*)&As[(wm * 64 + mt * 16 + c) * 32 + qd * 8];
        #pragma unroll
        for (int nt = 0; nt < 4; ++nt)
            bf[nt] = *(const short8*)&Bs[(wn * 64 + nt * 16 + c) * 32 + qd * 8];
        #pragma unroll
        for (int mt = 0; mt < 4; ++mt)
            #pragma unroll
            for (int nt = 0; nt < 4; ++nt)
                acc[mt][nt] = __builtin_amdgcn_mfma_f32_16x16x32_bf16(af[mt], bf[nt], acc[mt][nt], 0, 0, 0);
        __syncthreads();
    }

    // epilogue: n -> (mat, h, e); m -> (b, s)
    #pragma unroll
    for (int mt = 0; mt < 4; ++mt) {
        const int mbase = m0 + wm * 64 + mt * 16 + qd * 4;
        const int b = mbase >> 11;
        #pragma unroll
        for (int nt = 0; nt < 4; ++nt) {
            const int n = n0 + wn * 64 + nt * 16 + c;
            const int mat = n >> 10;
            const int idx = n & 1023;
            const int h = idx >> 6, e = idx & 63;
            const float bias = (mat == 0 ? bq : (mat == 1 ? bk : bv))[idx];
            if (mat == 2) {
                const int s = mbase & 2047;
                u16x4 pv;
                pv.x = f2bf(acc[mt][nt][0] + bias);
                pv.y = f2bf(acc[mt][nt][1] + bias);
                pv.z = f2bf(acc[mt][nt][2] + bias);
                pv.w = f2bf(acc[mt][nt][3] + bias);
                *(u16x4*)(vto + ((size_t)((b * 16 + h) * 64 + e)) * 2048 + s) = pv;
            } else {
                const float scale = (mat == 0) ? 0.125f : 1.0f;
                u16* dst = (mat == 0) ? qo : ko;
                #pragma unroll
                for (int r = 0; r < 4; ++r) {
                    const int s = (mbase + r) & 2047;
                    dst[((size_t)((b * 16 + h) * 2048 + s)) * 64 + e] =
                        f2bf((acc[mt][nt][r] + bias) * scale);
                }
            }
        }
    }
}

// ---------------- flash attention, S^T formulation ----------------
// Per block: 64 Q rows (16/wave), 64-key tiles.
// S^T = K Q^T  => C-layout: lane col c = QUERY, row qd*4+r = KEY.
// O^T = V^T P^T => A-frag from Vt (contiguous), B-frag from Ps[q][t] (contiguous).
__global__ __launch_bounds__(256) void flash_kernel(
    const u16* __restrict__ Q,   // [32][2048][64], pre-scaled by 1/8
    const u16* __restrict__ K,   // [32][2048][64]
    const u16* __restrict__ Vt,  // [32][64][2048]
    u16* __restrict__ ctx)       // [4096][1024] = [b*2048+s][h*64+e]
{
    __shared__ __align__(16) u16 Ks[64 * 72];
    __shared__ __align__(16) u16 Vs[64 * 72];
    __shared__ __align__(16) u16 Ps[4 * 16 * 72];   // per-wave [16 q][72]
    const int tid = threadIdx.x, lane = tid & 63, w = tid >> 6;
    const int c = lane & 15, qd = lane >> 4;
    const int bh = blockIdx.y;
    const int q0 = blockIdx.x * 64;
    const int b = bh >> 4, h = bh & 15;
    const u16* Qh = Q + (size_t)bh * 2048 * 64;
    const u16* Kh = K + (size_t)bh * 2048 * 64;
    const u16* Vh = Vt + (size_t)bh * 64 * 2048;
    u16* Pw = &Ps[w * 16 * 72];

    // Q B-fragments pinned in registers: lane c owns query q0 + w*16 + c
    const int myq = q0 + w * 16 + c;
    short8 qa[2];
    #pragma unroll
    for (int kb = 0; kb < 2; ++kb)
        qa[kb] = *(const short8*)&Qh[(size_t)myq * 64 + kb * 32 + qd * 8];

    f32x4 o[4];                     // O^T: lane holds q=c, e = mt*16 + qd*4 + r
    #pragma unroll
    for (int mt = 0; mt < 4; ++mt) o[mt] = f32x4{0.f, 0.f, 0.f, 0.f};
    float mrow = -__builtin_inff(), lrow = 0.f;

    for (int t0 = 0; t0 < 2048; t0 += 64) {
        // stage K tile [64 t][64 d] -> Ks[64][72]; Vt tile [64 e][64 t] -> Vs[64][72]
        #pragma unroll
        for (int i = 0; i < 2; ++i) {
            int sl = i * 256 + tid;
            int r = sl >> 3, p = sl & 7;
            *(short8*)&Ks[r * 72 + p * 8] = *(const short8*)&Kh[(size_t)(t0 + r) * 64 + p * 8];
            *(short8*)&Vs[r * 72 + p * 8] = *(const short8*)&Vh[(size_t)r * 2048 + t0 + p * 8];
        }
        __syncthreads();

        // S^T = K Q^T : A = K rows (m=t), B = Q (n=q)
        f32x4 sc[4];
        #pragma unroll
        for (int mt = 0; mt < 4; ++mt) sc[mt] = f32x4{0.f, 0.f, 0.f, 0.f};
        #pragma unroll
        for (int mt = 0; mt < 4; ++mt)
            #pragma unroll
            for (int kb = 0; kb < 2; ++kb) {
                short8 kf = *(const short8*)&Ks[(mt * 16 + c) * 72 + kb * 32 + qd * 8];
                sc[mt] = __builtin_amdgcn_mfma_f32_16x16x32_bf16(kf, qa[kb], sc[mt], 0, 0, 0);
            }

        // online softmax: all 16 keys of this lane are in registers; reduce
        // in-lane then across the 4 qd-groups (lanes c, c+16, c+32, c+48).
        float mloc = fmaxf(fmaxf(fmaxf(sc[0][0], sc[0][1]), fmaxf(sc[0][2], sc[0][3])),
                           fmaxf(fmaxf(sc[1][0], sc[1][1]), fmaxf(sc[1][2], sc[1][3])));
        mloc = fmaxf(mloc,
               fmaxf(fmaxf(fmaxf(sc[2][0], sc[2][1]), fmaxf(sc[2][2], sc[2][3])),
                     fmaxf(fmaxf(sc[3][0], sc[3][1]), fmaxf(sc[3][2], sc[3][3]))));
        mloc = fmaxf(mloc, __shfl_xor(mloc, 16, 64));
        mloc = fmaxf(mloc, __shfl_xor(mloc, 32, 64));

        const float mn = fmaxf(mrow, mloc);
        const float alpha = __expf(mrow - mn);
        mrow = mn;

        float rs = 0.f;
        #pragma unroll
        for (int mt = 0; mt < 4; ++mt) {
            u16x4 pk;
            #pragma unroll
            for (int r = 0; r < 4; ++r) {
                float p = __expf(sc[mt][r] - mn);
                rs += p;
                ((u16*)&pk)[r] = f2bf(p);
            }
            // P^T reg r = key t0 + mt*16 + qd*4 + r  ->  Ps[q=c][t], b64 write
            *(u16x4*)&Pw[c * 72 + mt * 16 + qd * 4] = pk;
        }
        rs += __shfl_xor(rs, 16, 64);
        rs += __shfl_xor(rs, 32, 64);
        lrow = lrow * alpha + rs;

        #pragma unroll
        for (int mt = 0; mt < 4; ++mt) {
            o[mt][0] *= alpha; o[mt][1] *= alpha;
            o[mt][2] *= alpha; o[mt][3] *= alpha;
        }

        // O^T += V^T P^T : A = Vs rows (m=e), B = Ps rows (n=q)
        #pragma unroll
        for (int kb = 0; kb < 2; ++kb) {
            short8 pb = *(const short8*)&Pw[c * 72 + kb * 32 + qd * 8];
            #pragma unroll
            for (int mt = 0; mt < 4; ++mt) {
                short8 vf = *(const short8*)&Vs[(mt * 16 + c) * 72 + kb * 32 + qd * 8];
                o[mt] = __builtin_amdgcn_mfma_f32_16x16x32_bf16(vf, pb, o[mt], 0, 0, 0);
            }
        }
        __syncthreads();
    }

    // normalize + store: lane holds q = myq, e = mt*16 + qd*4 + r (r consecutive)
    const float inv = 1.0f / lrow;
    #pragma unroll
    for (int mt = 0; mt < 4; ++mt) {
        u16x4 ov;
        ov.x = f2bf(o[mt][0] * inv);
        ov.y = f2bf(o[mt][1] * inv);
        ov.z = f2bf(o[mt][2] * inv);
        ov.w = f2bf(o[mt][3] * inv);
        *(u16x4*)&ctx[((size_t)(b * 2048 + myq)) * 1024 + h * 64 + mt * 16 + qd * 4] = ov;
    }
}

// ---------------- output projection: ctx[4096,1024] x Wo^T[1024,1024] + bo ----------------
__global__ __launch_bounds__(256) void gemm_out_kernel(
    const u16* __restrict__ A, const u16* __restrict__ Wt,
    const float* __restrict__ bo, float* __restrict__ out)
{
    __shared__ __align__(16) u16 As[128 * 32];
    __shared__ __align__(16) u16 Bs[128 * 32];
    const int tid = threadIdx.x;
    const int lane = tid & 63;
    const int wv = tid >> 6;
    const int wm = wv & 1, wn = wv >> 1;
    const int m0 = blockIdx.x * 128;
    const int n0 = blockIdx.y * 128;
    const int c = lane & 15, qd = lane >> 4;

    f32x4 acc[4][4];
    #pragma unroll
    for (int a = 0; a < 4; ++a)
        #pragma unroll
        for (int b2 = 0; b2 < 4; ++b2) acc[a][b2] = f32x4{0.f, 0.f, 0.f, 0.f};

    const u16* Ab = A + (size_t)m0 * 1024;
    const u16* Wb = Wt + (size_t)n0 * 1024;

    for (int kt = 0; kt < 1024; kt += 32) {
        #pragma unroll
        for (int i = 0; i < 2; ++i) {
            int slot = i * 256 + tid;
            int row = slot >> 2, part = slot & 3;
            gload_lds16(Ab + (size_t)row * 1024 + kt + part * 8, &As[slot * 8]);
            gload_lds16(Wb + (size_t)row * 1024 + kt + part * 8, &Bs[slot * 8]);
        }
        __syncthreads();
        short8 af[4], bf[4];
        #pragma unroll
        for (int mt = 0; mt < 4; ++mt)
            af[mt] = *(const short8*)&As[(wm * 64 + mt * 16 + c) * 32 + qd * 8];
        #pragma unroll
        for (int nt = 0; nt < 4; ++nt)
            bf[nt] = *(const short8*)&Bs[(wn * 64 + nt * 16 + c) * 32 + qd * 8];
        #pragma unroll
        for (int mt = 0; mt < 4; ++mt)
            #pragma unroll
            for (int nt = 0; nt < 4; ++nt)
                acc[mt][nt] = __builtin_amdgcn_mfma_f32_16x16x32_bf16(af[mt], bf[nt], acc[mt][nt], 0, 0, 0);
        __syncthreads();
    }

    #pragma unroll
    for (int mt = 0; mt < 4; ++mt) {
        const int mbase = m0 + wm * 64 + mt * 16 + qd * 4;
        #pragma unroll
        for (int nt = 0; nt < 4; ++nt) {
            const int n = n0 + wn * 64 + nt * 16 + c;
            const float bias = bo[n];
            #pragma unroll
            for (int r = 0; r < 4; ++r)
                out[(size_t)(mbase + r) * 1024 + n] = acc[mt][nt][r] + bias;
        }
    }
}

extern "C" void kernel_launch(void* const* d_in, const int* in_sizes, int n_in,
                              void* d_out, int out_size, void* d_ws, size_t ws_size,
                              hipStream_t stream) {
    const float* x  = (const float*)d_in[0];
    const float* Wq = (const float*)d_in[1];
    const float* bq = (const float*)d_in[2];
    const float* Wk = (const float*)d_in[3];
    const float* bk = (const float*)d_in[4];
    const float* Wv = (const float*)d_in[5];
    const float* bv = (const float*)d_in[6];
    const float* Wo = (const float*)d_in[7];
    const float* bo = (const float*)d_in[8];
    float* out = (float*)d_out;

    u16* ws    = (u16*)d_ws;
    u16* xb    = ws;                          // 4096*1024
    u16* wqkv  = xb + 4096 * 1024;            // 3072*1024  (rows n=(mat,h,e), cols k=d)
    u16* wot   = wqkv + 3072 * 1024;          // 1024*1024  (rows n=o, cols k=d)
    u16* qws   = wot + 1024 * 1024;           // 32*2048*64
    u16* kws   = qws + 4194304;               // 32*2048*64
    u16* vtws  = kws + 4194304;               // 32*64*2048
    u16* ctxws = vtws + 4194304;              // 4096*1024

    cast_x_kernel<<<4096, 256, 0, stream>>>(x, xb);
    transpose_cast_kernel<<<dim3(16, 1, 16), 256, 0, stream>>>(Wq, wqkv, 1024, 64);
    transpose_cast_kernel<<<dim3(16, 1, 16), 256, 0, stream>>>(Wk, wqkv + 1024 * 1024, 1024, 64);
    transpose_cast_kernel<<<dim3(16, 1, 16), 256, 0, stream>>>(Wv, wqkv + 2 * 1024 * 1024, 1024, 64);
    transpose_cast_kernel<<<dim3(16, 16, 1), 256, 0, stream>>>(Wo, wot, 1024, 1024);
    gemm_qkv_kernel<<<dim3(32, 24), 256, 0, stream>>>(xb, wqkv, bq, bk, bv, qws, kws, vtws);
    flash_kernel<<<dim3(32, 32), 256, 0, stream>>>(qws, kws, vtws, ctxws);
    gemm_out_kernel<<<dim3(32, 8), 256, 0, stream>>>(ctxws, wot, bo, out);
}